// Round 1
// baseline (93.712 us; speedup 1.0000x reference)
//
#include <hip/hip_runtime.h>

#define NN 50000      // nodes
#define EE 100000     // edges
#define RR 64         // relations
#define DD 50         // feature dim

// One 64-lane wave per edge. Lane k (k<50) computes msg[k] = sum_d h[src][d]*W[rel][d][k]
// and atomically accumulates into acc[dst*50+k].
__global__ void rgcn_edge_kernel(const float* __restrict__ h,
                                 const float* __restrict__ weight,
                                 const int* __restrict__ src_idx,
                                 const int* __restrict__ dst_idx,
                                 const int* __restrict__ rel_type,
                                 float* __restrict__ acc,
                                 int E) {
    int wave = (int)((blockIdx.x * blockDim.x + threadIdx.x) >> 6);
    int lane = threadIdx.x & 63;
    if (wave >= E) return;

    int s = src_idx[wave];
    int r = rel_type[wave];
    int dst = dst_idx[wave];

    const float* __restrict__ hs = h + (size_t)s * DD;
    const float* __restrict__ W  = weight + (size_t)r * DD * DD;

    if (lane < DD) {
        float m = 0.f;
        #pragma unroll
        for (int d = 0; d < DD; ++d) {
            // hs[d] is wave-uniform (broadcast); W row read is lane-coalesced, L2-resident.
            m = fmaf(hs[d], W[d * DD + lane], m);
        }
        atomicAdd(&acc[(size_t)dst * DD + lane], m);
    }
}

// out = relu(acc + bias)
__global__ void finalize_kernel(const float* __restrict__ acc,
                                const float* __restrict__ bias,
                                float* __restrict__ out,
                                int total) {
    int i = (int)(blockIdx.x * blockDim.x + threadIdx.x);
    if (i < total) {
        float v = acc[i] + bias[i % DD];
        out[i] = v > 0.f ? v : 0.f;
    }
}

extern "C" void kernel_launch(void* const* d_in, const int* in_sizes, int n_in,
                              void* d_out, int out_size, void* d_ws, size_t ws_size,
                              hipStream_t stream) {
    const float* h      = (const float*)d_in[0];
    const float* weight = (const float*)d_in[1];
    const float* bias   = (const float*)d_in[2];
    const int*   src    = (const int*)d_in[3];
    const int*   dst    = (const int*)d_in[4];
    const int*   rel    = (const int*)d_in[5];

    float* acc = (float*)d_ws;   // N*D floats = 10 MB accumulator
    float* out = (float*)d_out;

    const int E = in_sizes[3];
    const int total = NN * DD;

    hipMemsetAsync(acc, 0, (size_t)total * sizeof(float), stream);

    // 4 waves (edges) per 256-thread block
    int edge_blocks = (E + 3) / 4;
    rgcn_edge_kernel<<<edge_blocks, 256, 0, stream>>>(h, weight, src, dst, rel, acc, E);

    int fin_blocks = (total + 255) / 256;
    finalize_kernel<<<fin_blocks, 256, 0, stream>>>(acc, bias, out, total);
}